// Round 23
// baseline (124.470 us; speedup 1.0000x reference)
//
#include <hip/hip_runtime.h>

#define N_NODES 4096
#define HID 256
#define NHEADS 8
#define HDIM 32
#define EPSV 1e-5f
// static softmax max (logits bounded ~|6|); in log2 domain: 8*log2(e)
#define M2LOG 11.541560327111707f

typedef __bf16 bf16x8 __attribute__((ext_vector_type(8)));
typedef __bf16 bf16x4 __attribute__((ext_vector_type(4)));
typedef float f32x4 __attribute__((ext_vector_type(4)));

__device__ inline float fexp2(float x) {
    float r;
    asm("v_exp_f32 %0, %1" : "=v"(r) : "v"(x));
    return r;
}

__device__ inline uint4 pack8(float4 a, float4 b) {
    bf16x8 p;
    p[0]=(__bf16)a.x; p[1]=(__bf16)a.y; p[2]=(__bf16)a.z; p[3]=(__bf16)a.w;
    p[4]=(__bf16)b.x; p[5]=(__bf16)b.y; p[6]=(__bf16)b.z; p[7]=(__bf16)b.w;
    return __builtin_bit_cast(uint4, p);
}
__device__ inline float4 nmad4(float4 x, float4 s, float4 sh) {
    return make_float4(fmaf(x.x,s.x,sh.x), fmaf(x.y,s.y,sh.y),
                       fmaf(x.z,s.z,sh.z), fmaf(x.w,s.w,sh.w));
}
__device__ inline float bflo(unsigned u) { return __builtin_bit_cast(float, u << 16); }
__device__ inline float bfhi(unsigned u) { return __builtin_bit_cast(float, u & 0xFFFF0000u); }

// ---------------------------------------------------------------------------
// bf16 MFMA GEMM, 64x32 tiles. Optional fused BatchNorm: norm_x normalizes X
// during staging; norm_r normalizes the residual. psum/pq emit partials.
// ---------------------------------------------------------------------------
__launch_bounds__(256)
__global__ void gemm_mfma(const float* __restrict__ X, const float* __restrict__ W,
                          const float* __restrict__ bias, const float* __restrict__ resid,
                          float* __restrict__ C,
                          const float* __restrict__ pSin, const float* __restrict__ pQin,
                          const float* __restrict__ gamin, const float* __restrict__ betin,
                          int norm_x, int norm_r,
                          float* __restrict__ psum, float* __restrict__ pq,
                          int M, int N, int K, float scale, int do_relu) {
    __shared__ uint4 xl[2][512];
    __shared__ uint4 wl[2][256];
    __shared__ __align__(16) float nsc[256];
    __shared__ __align__(16) float nsh[256];
    const int bm = blockIdx.x * 64, bn = blockIdx.y * 32;
    const int t = threadIdx.x;
    const int w = t >> 6, l = t & 63, g = l >> 4, nl = l & 15;
    const int srow = t >> 3, seg = t & 7;
    const int sx = (seg & 3) << 1;
    const int d0 = seg*64 + (srow ^ sx);
    const int d1 = seg*64 + ((srow + 32) ^ sx);
    const int dw = seg*32 + (srow ^ sx);
    const float* xp = X + (size_t)(bm + srow)*K + seg*8;
    const float* wp = W + (size_t)(bn + srow)*K + seg*8;
    const size_t rstep = (size_t)32*K;

    if (pSin) {
        float s = 0.f, q = 0.f;
        #pragma unroll 8
        for (int b = 0; b < 64; ++b) { s += pSin[b*HID + t]; q += pQin[b*HID + t]; }
        const float m = s * (1.f/4096.f);
        const float rstd = rsqrtf(q*(1.f/4096.f) - m*m + EPSV);
        const float sc = rstd * gamin[t];
        nsc[t] = sc;
        nsh[t] = fmaf(-m, sc, betin[t]);
        __syncthreads();
    }

    f32x4 acc[2];
    acc[0] = (f32x4){0.f,0.f,0.f,0.f};
    acc[1] = (f32x4){0.f,0.f,0.f,0.f};

    {
        float4 x0 = *(const float4*)(xp),          x1 = *(const float4*)(xp + 4);
        float4 x2 = *(const float4*)(xp + rstep),  x3 = *(const float4*)(xp + rstep + 4);
        if (norm_x) {
            float4 s0 = *(const float4*)(nsc + seg*8), s1 = *(const float4*)(nsc + seg*8 + 4);
            float4 h0 = *(const float4*)(nsh + seg*8), h1 = *(const float4*)(nsh + seg*8 + 4);
            x0 = nmad4(x0,s0,h0); x1 = nmad4(x1,s1,h1);
            x2 = nmad4(x2,s0,h0); x3 = nmad4(x3,s1,h1);
        }
        float4 w0 = *(const float4*)(wp), w1 = *(const float4*)(wp + 4);
        xl[0][d0] = pack8(x0, x1); xl[0][d1] = pack8(x2, x3);
        wl[0][dw] = pack8(w0, w1);
    }
    __syncthreads();

    for (int k0 = 0; k0 < K; k0 += 64) {
        const int cur = (k0 >> 6) & 1;
        const bool nxt = (k0 + 64) < K;
        float4 nx0, nx1, nx2, nx3, nw0, nw1;
        if (nxt) {
            const int kk = k0 + 64;
            nx0 = *(const float4*)(xp + kk);          nx1 = *(const float4*)(xp + kk + 4);
            nx2 = *(const float4*)(xp + rstep + kk);  nx3 = *(const float4*)(xp + rstep + kk + 4);
            if (norm_x) {
                float4 s0 = *(const float4*)(nsc + kk + seg*8), s1 = *(const float4*)(nsc + kk + seg*8 + 4);
                float4 h0 = *(const float4*)(nsh + kk + seg*8), h1 = *(const float4*)(nsh + kk + seg*8 + 4);
                nx0 = nmad4(nx0,s0,h0); nx1 = nmad4(nx1,s1,h1);
                nx2 = nmad4(nx2,s0,h0); nx3 = nmad4(nx3,s1,h1);
            }
            nw0 = *(const float4*)(wp + kk);  nw1 = *(const float4*)(wp + kk + 4);
        }
        __builtin_amdgcn_s_setprio(1);
        #pragma unroll
        for (int ks = 0; ks < 2; ++ks) {
            bf16x8 af = __builtin_bit_cast(bf16x8, xl[cur][(ks*4 + g)*64 + ((w*16 + nl) ^ (g << 1))]);
            #pragma unroll
            for (int nf = 0; nf < 2; ++nf) {
                bf16x8 bfr = __builtin_bit_cast(bf16x8, wl[cur][(ks*4 + g)*32 + ((nf*16 + nl) ^ (g << 1))]);
                acc[nf] = __builtin_amdgcn_mfma_f32_16x16x32_bf16(af, bfr, acc[nf], 0, 0, 0);
            }
        }
        __builtin_amdgcn_s_setprio(0);
        if (nxt) {
            xl[cur^1][d0] = pack8(nx0, nx1); xl[cur^1][d1] = pack8(nx2, nx3);
            wl[cur^1][dw] = pack8(nw0, nw1);
        }
        __syncthreads();
    }

    float colS[2] = {0.f,0.f}, colQ[2] = {0.f,0.f};
    #pragma unroll
    for (int nf = 0; nf < 2; ++nf) {
        const int col = bn + nf*16 + nl;
        const float bb = bias[col];
        float rs = 1.f, rh = 0.f;
        if (norm_r) { rs = nsc[col]; rh = nsh[col]; }
        #pragma unroll
        for (int r = 0; r < 4; ++r) {
            const int row = bm + w*16 + g*4 + r;
            float v = acc[nf][r] + bb;
            if (resid) {
                float rv = resid[(size_t)row*N + col];
                v += norm_r ? fmaf(rv, rs, rh) : rv;
            }
            v *= scale;
            if (do_relu) v = fmaxf(v, 0.f);
            C[(size_t)row*N + col] = v;
            colS[nf] += v;
            colQ[nf] = fmaf(v, v, colQ[nf]);
        }
    }
    if (psum) {
        float* cs = (float*)&xl[0][0];
        float* cq = cs + 512;
        #pragma unroll
        for (int nf = 0; nf < 2; ++nf) {
            const int idx = (w*4 + g)*32 + nf*16 + nl;
            cs[idx] = colS[nf];
            cq[idx] = colQ[nf];
        }
        __syncthreads();
        if (t < 32) {
            float s = 0.f, q = 0.f;
            #pragma unroll
            for (int i = 0; i < 16; ++i) { s += cs[i*32 + t]; q += cq[i*32 + t]; }
            psum[blockIdx.x*HID + bn + t] = s;
            pq[blockIdx.x*HID + bn + t]   = q;
        }
    }
}

// ---------------------------------------------------------------------------
// Wo GEMM (64x32 tiles) with fused split-m combine from bf16 Opart
// (d'-permuted layout); W staged with the matching permutation. bn1 partials.
// ---------------------------------------------------------------------------
__launch_bounds__(256)
__global__ void gemm_wo(const __bf16* __restrict__ Opart, const float* __restrict__ Lpart,
                        int nsplit, const float* __restrict__ W,
                        const float* __restrict__ bias, const float* __restrict__ resid,
                        float* __restrict__ C, float* __restrict__ psum, float* __restrict__ pq) {
    const int N = 256, K = 256;
    __shared__ uint4 xl[2][512];
    __shared__ uint4 wl[2][256];
    const int bm = blockIdx.x * 64, bn = blockIdx.y * 32;
    const int t = threadIdx.x;
    const int w = t >> 6, l = t & 63, g = l >> 4, nl = l & 15;
    const int srow = t >> 3, seg = t & 7;
    const int sx = (seg & 3) << 1;
    const int d0 = seg*64 + (srow ^ sx);
    const int d1 = seg*64 + ((srow + 32) ^ sx);
    const int dw = seg*32 + (srow ^ sx);
    const float* wrow = W + (size_t)(bn + srow)*K;

    auto cl = [&](int row, int kp, float4& a, float4& b) {
        const size_t flat = (size_t)row*256 + kp;
        const int hn = (int)(flat >> 5);
        float L = 0.f;
        float s0=0,s1=0,s2=0,s3=0,s4=0,s5=0,s6=0,s7=0;
        for (int z = 0; z < nsplit; ++z) {
            L += Lpart[z*32768 + hn];
            uint4 u = *(const uint4*)(Opart + (size_t)z*1048576 + flat);
            s0 += bflo(u.x); s1 += bfhi(u.x);
            s2 += bflo(u.y); s3 += bfhi(u.y);
            s4 += bflo(u.z); s5 += bfhi(u.z);
            s6 += bflo(u.w); s7 += bfhi(u.w);
        }
        const float inv = 1.f / L;
        a = make_float4(s0*inv, s1*inv, s2*inv, s3*inv);
        b = make_float4(s4*inv, s5*inv, s6*inv, s7*inv);
    };
    auto wld = [&](int kp, float4& a, float4& b) {
        const int kb = (kp & ~31) + ((kp >> 3) & 3)*4;
        a = *(const float4*)(wrow + kb);
        b = *(const float4*)(wrow + kb + 16);
    };

    f32x4 acc[2];
    acc[0] = (f32x4){0.f,0.f,0.f,0.f};
    acc[1] = (f32x4){0.f,0.f,0.f,0.f};

    {
        float4 x0, x1, x2, x3, w0, w1;
        cl(bm + srow,      seg*8, x0, x1);
        cl(bm + srow + 32, seg*8, x2, x3);
        wld(seg*8, w0, w1);
        xl[0][d0] = pack8(x0, x1); xl[0][d1] = pack8(x2, x3);
        wl[0][dw] = pack8(w0, w1);
    }
    __syncthreads();

    for (int k0 = 0; k0 < K; k0 += 64) {
        const int cur = (k0 >> 6) & 1;
        const bool nxt = (k0 + 64) < K;
        float4 nx0, nx1, nx2, nx3, nw0, nw1;
        if (nxt) {
            const int kp = k0 + 64 + seg*8;
            cl(bm + srow,      kp, nx0, nx1);
            cl(bm + srow + 32, kp, nx2, nx3);
            wld(kp, nw0, nw1);
        }
        __builtin_amdgcn_s_setprio(1);
        #pragma unroll
        for (int ks = 0; ks < 2; ++ks) {
            bf16x8 af = __builtin_bit_cast(bf16x8, xl[cur][(ks*4 + g)*64 + ((w*16 + nl) ^ (g << 1))]);
            #pragma unroll
            for (int nf = 0; nf < 2; ++nf) {
                bf16x8 bfr = __builtin_bit_cast(bf16x8, wl[cur][(ks*4 + g)*32 + ((nf*16 + nl) ^ (g << 1))]);
                acc[nf] = __builtin_amdgcn_mfma_f32_16x16x32_bf16(af, bfr, acc[nf], 0, 0, 0);
            }
        }
        __builtin_amdgcn_s_setprio(0);
        if (nxt) {
            xl[cur^1][d0] = pack8(nx0, nx1); xl[cur^1][d1] = pack8(nx2, nx3);
            wl[cur^1][dw] = pack8(nw0, nw1);
        }
        __syncthreads();
    }

    float colS[2] = {0.f,0.f}, colQ[2] = {0.f,0.f};
    #pragma unroll
    for (int nf = 0; nf < 2; ++nf) {
        const int col = bn + nf*16 + nl;
        const float bb = bias[col];
        #pragma unroll
        for (int r = 0; r < 4; ++r) {
            const int row = bm + w*16 + g*4 + r;
            float v = acc[nf][r] + bb + resid[(size_t)row*N + col];
            C[(size_t)row*N + col] = v;
            colS[nf] += v;
            colQ[nf] = fmaf(v, v, colQ[nf]);
        }
    }
    {
        float* cs = (float*)&xl[0][0];
        float* cq = cs + 512;
        #pragma unroll
        for (int nf = 0; nf < 2; ++nf) {
            const int idx = (w*4 + g)*32 + nf*16 + nl;
            cs[idx] = colS[nf];
            cq[idx] = colQ[nf];
        }
        __syncthreads();
        if (t < 32) {
            float s = 0.f, q = 0.f;
            #pragma unroll
            for (int i = 0; i < 16; ++i) { s += cs[i*32 + t]; q += cq[i*32 + t]; }
            psum[blockIdx.x*HID + bn + t] = s;
            pq[blockIdx.x*HID + bn + t]   = q;
        }
    }
}

// ---------------------------------------------------------------------------
// Fused QKV3 (64x32 tiles, ONE kernel): X tile staged once per k-step for all
// three projections. q/k write bf16 hat [h][n][32]; v writes vT directly.
// ---------------------------------------------------------------------------
__launch_bounds__(256)
__global__ void gemm_qkv3(const float* __restrict__ X,
                          const float* __restrict__ Wq, const float* __restrict__ Wk,
                          const float* __restrict__ Wv, const float* __restrict__ bq,
                          const float* __restrict__ bk, const float* __restrict__ bv,
                          __bf16* __restrict__ qhat, __bf16* __restrict__ khat,
                          __bf16* __restrict__ vT) {
    const int K = 256;
    __shared__ uint4 xl[2][512];
    __shared__ uint4 wql[2][256];
    __shared__ uint4 wkl[2][256];
    __shared__ uint4 wvl[2][256];
    const int bm = blockIdx.x * 64, bn = blockIdx.y * 32;
    const int t = threadIdx.x;
    const int w = t >> 6, l = t & 63, g = l >> 4, nl = l & 15;
    const int srow = t >> 3, seg = t & 7;
    const int sx = (seg & 3) << 1;
    const int d0 = seg*64 + (srow ^ sx);
    const int d1 = seg*64 + ((srow + 32) ^ sx);
    const int dw = seg*32 + (srow ^ sx);
    const float* xp  = X  + (size_t)(bm + srow)*K + seg*8;
    const float* wqp = Wq + (size_t)(bn + srow)*K + seg*8;
    const float* wkp = Wk + (size_t)(bn + srow)*K + seg*8;
    const float* wvp = Wv + (size_t)(bn + srow)*K + seg*8;
    const size_t rstep = (size_t)32*K;

    f32x4 aq[2], ak[2], av[2];
    #pragma unroll
    for (int nf = 0; nf < 2; ++nf) {
        aq[nf] = (f32x4){0.f,0.f,0.f,0.f};
        ak[nf] = (f32x4){0.f,0.f,0.f,0.f};
        av[nf] = (f32x4){0.f,0.f,0.f,0.f};
    }

    {
        float4 x0 = *(const float4*)(xp),          x1 = *(const float4*)(xp + 4);
        float4 x2 = *(const float4*)(xp + rstep),  x3 = *(const float4*)(xp + rstep + 4);
        float4 q0 = *(const float4*)(wqp), q1 = *(const float4*)(wqp + 4);
        float4 k0 = *(const float4*)(wkp), k1 = *(const float4*)(wkp + 4);
        float4 v0 = *(const float4*)(wvp), v1 = *(const float4*)(wvp + 4);
        xl[0][d0] = pack8(x0, x1); xl[0][d1] = pack8(x2, x3);
        wql[0][dw] = pack8(q0, q1);
        wkl[0][dw] = pack8(k0, k1);
        wvl[0][dw] = pack8(v0, v1);
    }
    __syncthreads();

    for (int k0 = 0; k0 < K; k0 += 64) {
        const int cur = (k0 >> 6) & 1;
        const bool nxt = (k0 + 64) < K;
        float4 nx0, nx1, nx2, nx3, nq0, nq1, nk0, nk1, nv0, nv1;
        if (nxt) {
            const int kk = k0 + 64;
            nx0 = *(const float4*)(xp + kk);          nx1 = *(const float4*)(xp + kk + 4);
            nx2 = *(const float4*)(xp + rstep + kk);  nx3 = *(const float4*)(xp + rstep + kk + 4);
            nq0 = *(const float4*)(wqp + kk);  nq1 = *(const float4*)(wqp + kk + 4);
            nk0 = *(const float4*)(wkp + kk);  nk1 = *(const float4*)(wkp + kk + 4);
            nv0 = *(const float4*)(wvp + kk);  nv1 = *(const float4*)(wvp + kk + 4);
        }
        __builtin_amdgcn_s_setprio(1);
        #pragma unroll
        for (int ks = 0; ks < 2; ++ks) {
            bf16x8 af = __builtin_bit_cast(bf16x8, xl[cur][(ks*4 + g)*64 + ((w*16 + nl) ^ (g << 1))]);
            #pragma unroll
            for (int nf = 0; nf < 2; ++nf) {
                const int wi = (ks*4 + g)*32 + ((nf*16 + nl) ^ (g << 1));
                bf16x8 bq8 = __builtin_bit_cast(bf16x8, wql[cur][wi]);
                bf16x8 bk8 = __builtin_bit_cast(bf16x8, wkl[cur][wi]);
                bf16x8 bv8 = __builtin_bit_cast(bf16x8, wvl[cur][wi]);
                aq[nf] = __builtin_amdgcn_mfma_f32_16x16x32_bf16(af, bq8, aq[nf], 0, 0, 0);
                ak[nf] = __builtin_amdgcn_mfma_f32_16x16x32_bf16(af, bk8, ak[nf], 0, 0, 0);
                av[nf] = __builtin_amdgcn_mfma_f32_16x16x32_bf16(af, bv8, av[nf], 0, 0, 0);
            }
        }
        __builtin_amdgcn_s_setprio(0);
        if (nxt) {
            xl[cur^1][d0] = pack8(nx0, nx1); xl[cur^1][d1] = pack8(nx2, nx3);
            wql[cur^1][dw] = pack8(nq0, nq1);
            wkl[cur^1][dw] = pack8(nk0, nk1);
            wvl[cur^1][dw] = pack8(nv0, nv1);
        }
        __syncthreads();
    }

    const float qscale = 0.25506595325f;   // 32^-0.5 * log2(e)
    #pragma unroll
    for (int nf = 0; nf < 2; ++nf) {
        const int col = bn + nf*16 + nl;
        const float bbq = bq[col], bbk = bk[col], bbv = bv[col];
        const int dd = col & 31;
        #pragma unroll
        for (int r = 0; r < 4; ++r) {
            const int row = bm + w*16 + g*4 + r;
            const int hh = row >> 9;
            const int nn = ((row & 511) << 3) | (col >> 5);
            qhat[((size_t)(hh*4096 + nn))*32 + dd] = (__bf16)((aq[nf][r] + bbq) * qscale);
            khat[((size_t)(hh*4096 + nn))*32 + dd] = (__bf16)(ak[nf][r] + bbk);
            vT[((size_t)(hh*32 + dd))*4096 + nn]   = (__bf16)(av[nf][r] + bbv);
        }
    }
}

// ---------------------------------------------------------------------------
// All-heads flash attention with 2-step-deep A prefetch and counted-wait
// barriers: A loads for step s+2 issued as named ping-pong regs (no copies),
// per-step barrier is lgkmcnt(0)+s_barrier only -> the prefetch stays in
// flight across two barriers (~2 steps of HBM-latency cover). Otherwise
// identical to the best-measured R17/R18 structure.
// ---------------------------------------------------------------------------
__launch_bounds__(512, 2)
__global__ void attn_mfma(const __bf16* __restrict__ qh_, const __bf16* __restrict__ kh,
                          const __bf16* __restrict__ vT, const float* __restrict__ A,
                          __bf16* __restrict__ Opart, float* __restrict__ Lpart, int mlen) {
    __shared__ float A_lds[2][64][68];       // 34.8 KB, shared by all 8 heads
    __shared__ uint4 p_lds[8][4][64];        // 32 KB, per-wave P exchange

    const int t = threadIdx.x;
    const int w = t >> 6, l = t & 63;        // wave = head
    const int g = l >> 4, nl = l & 15;
    const int n0 = blockIdx.x * 64;
    const int z = blockIdx.y;
    const int m_begin = z * mlen;
    const int nsteps = mlen >> 6;

    bf16x8 qf[4];
    #pragma unroll
    for (int nf = 0; nf < 4; ++nf)
        qf[nf] = *(const bf16x8*)(qh_ + ((size_t)(w*4096 + n0 + nf*16 + nl))*32 + g*8);

    f32x4 oacc[4][2];
    #pragma unroll
    for (int nf = 0; nf < 4; ++nf) {
        oacc[nf][0] = (f32x4){0.f,0.f,0.f,0.f};
        oacc[nf][1] = (f32x4){0.f,0.f,0.f,0.f};
    }
    float Li[4] = {0.f, 0.f, 0.f, 0.f};

    const int aq = t >> 3, am = (t & 7) * 8;
    const float* Abase = A + (size_t)(n0 + aq)*N_NODES + m_begin + am;
    const __bf16* kbase = kh + ((size_t)w*4096 + nl)*32 + g*8;
    const __bf16* vbase = vT + ((size_t)w*32 + nl)*4096 + g*8;

    // prologue: stage A step 0 to LDS; issue A step 1 into ping regs
    *(float4*)&A_lds[0][aq][am]   = *(const float4*)(Abase);
    *(float4*)&A_lds[0][aq][am+4] = *(const float4*)(Abase + 4);
    float4 arA0, arA1, arB0, arB1;
    {
        const int s1 = (1 < nsteps) ? 1 : 0;
        arA0 = *(const float4*)(Abase + s1*64);
        arA1 = *(const float4*)(Abase + s1*64 + 4);
    }
    asm volatile("s_waitcnt lgkmcnt(0)" ::: "memory");
    __builtin_amdgcn_s_barrier();

#define ATTN_STEP(S, ARU0, ARU1, ARP0, ARP1)                                          \
    {                                                                                 \
        const int cur = (S) & 1;                                                      \
        const int m0 = m_begin + (S)*64;                                              \
        const int sp = ((S) + 2 < nsteps) ? (S) + 2 : (nsteps - 1);                   \
        /* issue A for step S+2 (deep prefetch, floats across 2 barriers) */          \
        ARP0 = *(const float4*)(Abase + sp*64);                                       \
        ARP1 = *(const float4*)(Abase + sp*64 + 4);                                   \
        /* batch-issue ALL current-step K/V fragments, pin the issue point */         \
        bf16x8 kf[4], vf[4];                                                          \
        _Pragma("unroll")                                                             \
        for (int tt = 0; tt < 4; ++tt)                                                \
            kf[tt] = *(const bf16x8*)(kbase + (size_t)(m0 + tt*16)*32);               \
        _Pragma("unroll")                                                             \
        for (int half = 0; half < 2; ++half)                                          \
            _Pragma("unroll")                                                         \
            for (int dt = 0; dt < 2; ++dt)                                            \
                vf[half*2+dt] = *(const bf16x8*)(vbase + (size_t)dt*16*4096 + m0 + half*32); \
        __builtin_amdgcn_sched_barrier(0);                                            \
        _Pragma("unroll")                                                             \
        for (int half = 0; half < 2; ++half) {                                        \
            _Pragma("unroll")                                                         \
            for (int tt2 = 0; tt2 < 2; ++tt2) {                                       \
                const int tt = half*2 + tt2;                                          \
                f32x4 st[4];                                                          \
                __builtin_amdgcn_s_setprio(1);                                        \
                _Pragma("unroll")                                                     \
                for (int nf = 0; nf < 4; ++nf) {                                      \
                    f32x4 zz = (f32x4){0.f,0.f,0.f,0.f};                              \
                    st[nf] = __builtin_amdgcn_mfma_f32_16x16x32_bf16(kf[tt], qf[nf], zz, 0, 0, 0); \
                }                                                                     \
                __builtin_amdgcn_s_setprio(0);                                        \
                _Pragma("unroll")                                                     \
                for (int nf = 0; nf < 4; ++nf) {                                      \
                    const f32x4 a4 = *(const f32x4*)&A_lds[cur][nf*16 + nl][tt*16 + g*4]; \
                    float p0 = fexp2(fmaf(st[nf][0], a4[0], -M2LOG));                 \
                    float p1 = fexp2(fmaf(st[nf][1], a4[1], -M2LOG));                 \
                    float p2 = fexp2(fmaf(st[nf][2], a4[2], -M2LOG));                 \
                    float p3 = fexp2(fmaf(st[nf][3], a4[3], -M2LOG));                 \
                    Li[nf] += (p0 + p1) + (p2 + p3);                                  \
                    bf16x4 pk;                                                        \
                    pk[0] = (__bf16)p0; pk[1] = (__bf16)p1;                           \
                    pk[2] = (__bf16)p2; pk[3] = (__bf16)p3;                           \
                    const int gm = tt2*2 + (g >> 1);                                  \
                    *(bf16x4*)((char*)&p_lds[w][nf][0] + (gm*16 + (nl ^ (gm << 1)))*16 + (g & 1)*8) = pk; \
                }                                                                     \
            }                                                                         \
            __builtin_amdgcn_s_setprio(1);                                            \
            _Pragma("unroll")                                                         \
            for (int nf = 0; nf < 4; ++nf) {                                          \
                bf16x8 pf = __builtin_bit_cast(bf16x8, p_lds[w][nf][g*16 + (nl ^ (g << 1))]); \
                oacc[nf][0] = __builtin_amdgcn_mfma_f32_16x16x32_bf16(vf[half*2+0], pf, oacc[nf][0], 0, 0, 0); \
                oacc[nf][1] = __builtin_amdgcn_mfma_f32_16x16x32_bf16(vf[half*2+1], pf, oacc[nf][1], 0, 0, 0); \
            }                                                                         \
            __builtin_amdgcn_s_setprio(0);                                            \
        }                                                                             \
        /* write A(S+1) (loaded 1 step ago, latency long covered) to other buf */     \
        if ((S) + 1 < nsteps) {                                                       \
            *(float4*)&A_lds[cur^1][aq][am]   = ARU0;                                 \
            *(float4*)&A_lds[cur^1][aq][am+4] = ARU1;                                 \
        }                                                                             \
        /* counted-wait barrier: LDS drained, the S+2 A loads stay in flight */       \
        asm volatile("s_waitcnt lgkmcnt(0)" ::: "memory");                            \
        __builtin_amdgcn_s_barrier();                                                 \
    }

    for (int s = 0; s < nsteps; s += 2) {
        ATTN_STEP(s,     arA0, arA1, arB0, arB1);
        ATTN_STEP(s + 1, arB0, arB1, arA0, arA1);
    }
#undef ATTN_STEP

    // epilogue: bf16 d'-packed partials (coalesced 16B stores) + L
    #pragma unroll
    for (int nf = 0; nf < 4; ++nf) {
        Li[nf] += __shfl_xor(Li[nf], 16);
        Li[nf] += __shfl_xor(Li[nf], 32);
        const int nq = n0 + nf*16 + nl;
        __bf16* ob = Opart + ((size_t)(z*NHEADS + w)*4096 + nq)*32;
        bf16x8 pk8;
        #pragma unroll
        for (int j = 0; j < 4; ++j) {
            pk8[j]     = (__bf16)oacc[nf][0][j];
            pk8[4 + j] = (__bf16)oacc[nf][1][j];
        }
        *(bf16x8*)(ob + g*8) = pk8;
        if (g == 0)
            Lpart[(z*NHEADS + w)*4096 + nq] = Li[nf];
    }
}

// ---------------------------------------------------------------------------
// Fused BatchNorm finalize + apply: per-block stats reduce, then apply.
// ---------------------------------------------------------------------------
__launch_bounds__(256)
__global__ void bnorm_fin_apply(const float* __restrict__ X,
                                const float* __restrict__ pS, const float* __restrict__ pQ,
                                const float* __restrict__ gam, const float* __restrict__ bet,
                                float* __restrict__ Y) {
    __shared__ __align__(16) float sc[256];
    __shared__ __align__(16) float sh[256];
    const int t = threadIdx.x;
    {
        float s = 0.f, q = 0.f;
        #pragma unroll 8
        for (int b = 0; b < 64; ++b) { s += pS[b*HID + t]; q += pQ[b*HID + t]; }
        const float m = s * (1.f/4096.f);
        const float rstd = rsqrtf(q*(1.f/4096.f) - m*m + EPSV);
        const float scv = rstd * gam[t];
        sc[t] = scv;
        sh[t] = fmaf(-m, scv, bet[t]);
    }
    __syncthreads();
    const int base0 = (blockIdx.x * 256 + t) * 16;
    #pragma unroll
    for (int j = 0; j < 4; ++j) {
        const int base = base0 + j*4;
        const int c = base & (HID - 1);
        float4 x = *(const float4*)(X + base);
        float4 o;
        o.x = fmaf(x.x, sc[c+0], sh[c+0]);
        o.y = fmaf(x.y, sc[c+1], sh[c+1]);
        o.z = fmaf(x.z, sc[c+2], sh[c+2]);
        o.w = fmaf(x.w, sc[c+3], sh[c+3]);
        *(float4*)(Y + base) = o;
    }
}

// ---------------------------------------------------------------------------
extern "C" void kernel_launch(void* const* d_in, const int* in_sizes, int n_in,
                              void* d_out, int out_size, void* d_ws, size_t ws_size,
                              hipStream_t stream) {
    const float* A  = (const float*)d_in[0];
    const float* h  = (const float*)d_in[1];
    const float* Wq = (const float*)d_in[2];
    const float* bq = (const float*)d_in[3];
    const float* Wk = (const float*)d_in[4];
    const float* bk = (const float*)d_in[5];
    const float* Wv = (const float*)d_in[6];
    const float* bv = (const float*)d_in[7];
    const float* Wo = (const float*)d_in[8];
    const float* bo = (const float*)d_in[9];
    const float* W1 = (const float*)d_in[10];
    const float* c1 = (const float*)d_in[11];
    const float* W2 = (const float*)d_in[12];
    const float* c2 = (const float*)d_in[13];
    const float* g1 = (const float*)d_in[14];
    const float* be1= (const float*)d_in[15];
    const float* g2 = (const float*)d_in[16];
    const float* be2= (const float*)d_in[17];

    char* wsb = (char*)d_ws;
    const size_t MiB = (size_t)1 << 20;
    // Opart bf16: nsplit*2 MiB at offset 8 MiB.
    const int nsplit = (ws_size >= 26*MiB) ? 8 : (ws_size >= 18*MiB) ? 4 : 2;
    const int mlen = N_NODES / nsplit;

    __bf16* qhat = (__bf16*)(wsb + 0*MiB);
    __bf16* khat = (__bf16*)(wsb + 2*MiB);
    __bf16* vT   = (__bf16*)(wsb + 4*MiB);          // 2 MiB
    __bf16* Opart = (__bf16*)(wsb + 8*MiB);         // nsplit*2 MiB
    float* Lpart = (float*)(wsb + 8*MiB + (size_t)nsplit*2*MiB);
    char* statb  = wsb + 8*MiB + (size_t)nsplit*2*MiB + 1*MiB;
    float* partS1 = (float*)statb;
    float* partQ1 = partS1 + 64*HID;
    float* partS2 = partQ1 + 64*HID;
    float* partQ2 = partS2 + 64*HID;
    float* Y1 = (float*)(wsb + 4*MiB);   // over dead vT (4..8 MiB)
    float* F1 = (float*)(wsb + 8*MiB);   // over dead Opart (8..16 MiB)
    float* Y2 = (float*)(wsb + 0*MiB);   // over dead q/k hats (0..4 MiB)

    // QKV fused: X staged once for q/k/v; V transposed in epilogue
    gemm_qkv3<<<dim3(64, 8), 256, 0, stream>>>(h, Wq, Wk, Wv, bq, bk, bv, qhat, khat, vT);

    // all-heads split-m attention (A read-once, deep A prefetch, bf16 Opart)
    attn_mfma<<<dim3(64, nsplit), 512, 0, stream>>>(qhat, khat, vT, A, Opart, Lpart, mlen);

    // Wo projection with fused combine (permuted W staging) + residual(h) + bn1 partials
    gemm_wo<<<dim3(64, 8), 256, 0, stream>>>(Opart, Lpart, nsplit, Wo, bo, h, Y1, partS1, partQ1);

    // FFN1: X = bnorm1(Y1) computed per-block from partials, staged on the fly
    gemm_mfma<<<dim3(64, 16), 256, 0, stream>>>(Y1, W1, c1, nullptr, F1,
                                                partS1, partQ1, g1, be1, 1, 0,
                                                nullptr, nullptr, 4096, 512, 256, 1.f, 1);
    // FFN2: + bnorm1(Y1) residual, bnorm2 partials in epilogue
    gemm_mfma<<<dim3(64, 8), 256, 0, stream>>>(F1, W2, c2, Y1, Y2,
                                               partS1, partQ1, g1, be1, 0, 1,
                                               partS2, partQ2, 4096, 256, 512, 1.f, 0);

    // fused bnorm2 finalize + apply -> output
    bnorm_fin_apply<<<256, 256, 0, stream>>>(Y2, partS2, partQ2, g2, be2, (float*)d_out);
}

// Round 24
// 123.260 us; speedup vs baseline: 1.0098x; 1.0098x over previous
//
#include <hip/hip_runtime.h>

#define N_NODES 4096
#define HID 256
#define NHEADS 8
#define HDIM 32
#define EPSV 1e-5f
// static softmax max (logits bounded ~|6|); in log2 domain: 8*log2(e)
#define M2LOG 11.541560327111707f

typedef __bf16 bf16x8 __attribute__((ext_vector_type(8)));
typedef __bf16 bf16x4 __attribute__((ext_vector_type(4)));
typedef float f32x4 __attribute__((ext_vector_type(4)));

__device__ inline float fexp2(float x) {
    float r;
    asm("v_exp_f32 %0, %1" : "=v"(r) : "v"(x));
    return r;
}

__device__ inline uint4 pack8(float4 a, float4 b) {
    bf16x8 p;
    p[0]=(__bf16)a.x; p[1]=(__bf16)a.y; p[2]=(__bf16)a.z; p[3]=(__bf16)a.w;
    p[4]=(__bf16)b.x; p[5]=(__bf16)b.y; p[6]=(__bf16)b.z; p[7]=(__bf16)b.w;
    return __builtin_bit_cast(uint4, p);
}
__device__ inline float4 nmad4(float4 x, float4 s, float4 sh) {
    return make_float4(fmaf(x.x,s.x,sh.x), fmaf(x.y,s.y,sh.y),
                       fmaf(x.z,s.z,sh.z), fmaf(x.w,s.w,sh.w));
}
__device__ inline float bflo(unsigned u) { return __builtin_bit_cast(float, u << 16); }
__device__ inline float bfhi(unsigned u) { return __builtin_bit_cast(float, u & 0xFFFF0000u); }

// ---------------------------------------------------------------------------
// bf16 MFMA GEMM, 64x32 tiles. Optional fused BatchNorm: norm_x normalizes X
// during staging; norm_r normalizes the residual. psum/pq emit partials.
// ---------------------------------------------------------------------------
__launch_bounds__(256)
__global__ void gemm_mfma(const float* __restrict__ X, const float* __restrict__ W,
                          const float* __restrict__ bias, const float* __restrict__ resid,
                          float* __restrict__ C,
                          const float* __restrict__ pSin, const float* __restrict__ pQin,
                          const float* __restrict__ gamin, const float* __restrict__ betin,
                          int norm_x, int norm_r,
                          float* __restrict__ psum, float* __restrict__ pq,
                          int M, int N, int K, float scale, int do_relu) {
    __shared__ uint4 xl[2][512];
    __shared__ uint4 wl[2][256];
    __shared__ __align__(16) float nsc[256];
    __shared__ __align__(16) float nsh[256];
    const int bm = blockIdx.x * 64, bn = blockIdx.y * 32;
    const int t = threadIdx.x;
    const int w = t >> 6, l = t & 63, g = l >> 4, nl = l & 15;
    const int srow = t >> 3, seg = t & 7;
    const int sx = (seg & 3) << 1;
    const int d0 = seg*64 + (srow ^ sx);
    const int d1 = seg*64 + ((srow + 32) ^ sx);
    const int dw = seg*32 + (srow ^ sx);
    const float* xp = X + (size_t)(bm + srow)*K + seg*8;
    const float* wp = W + (size_t)(bn + srow)*K + seg*8;
    const size_t rstep = (size_t)32*K;

    if (pSin) {
        float s = 0.f, q = 0.f;
        #pragma unroll 8
        for (int b = 0; b < 64; ++b) { s += pSin[b*HID + t]; q += pQin[b*HID + t]; }
        const float m = s * (1.f/4096.f);
        const float rstd = rsqrtf(q*(1.f/4096.f) - m*m + EPSV);
        const float sc = rstd * gamin[t];
        nsc[t] = sc;
        nsh[t] = fmaf(-m, sc, betin[t]);
        __syncthreads();
    }

    f32x4 acc[2];
    acc[0] = (f32x4){0.f,0.f,0.f,0.f};
    acc[1] = (f32x4){0.f,0.f,0.f,0.f};

    {
        float4 x0 = *(const float4*)(xp),          x1 = *(const float4*)(xp + 4);
        float4 x2 = *(const float4*)(xp + rstep),  x3 = *(const float4*)(xp + rstep + 4);
        if (norm_x) {
            float4 s0 = *(const float4*)(nsc + seg*8), s1 = *(const float4*)(nsc + seg*8 + 4);
            float4 h0 = *(const float4*)(nsh + seg*8), h1 = *(const float4*)(nsh + seg*8 + 4);
            x0 = nmad4(x0,s0,h0); x1 = nmad4(x1,s1,h1);
            x2 = nmad4(x2,s0,h0); x3 = nmad4(x3,s1,h1);
        }
        float4 w0 = *(const float4*)(wp), w1 = *(const float4*)(wp + 4);
        xl[0][d0] = pack8(x0, x1); xl[0][d1] = pack8(x2, x3);
        wl[0][dw] = pack8(w0, w1);
    }
    __syncthreads();

    for (int k0 = 0; k0 < K; k0 += 64) {
        const int cur = (k0 >> 6) & 1;
        const bool nxt = (k0 + 64) < K;
        float4 nx0, nx1, nx2, nx3, nw0, nw1;
        if (nxt) {
            const int kk = k0 + 64;
            nx0 = *(const float4*)(xp + kk);          nx1 = *(const float4*)(xp + kk + 4);
            nx2 = *(const float4*)(xp + rstep + kk);  nx3 = *(const float4*)(xp + rstep + kk + 4);
            if (norm_x) {
                float4 s0 = *(const float4*)(nsc + kk + seg*8), s1 = *(const float4*)(nsc + kk + seg*8 + 4);
                float4 h0 = *(const float4*)(nsh + kk + seg*8), h1 = *(const float4*)(nsh + kk + seg*8 + 4);
                nx0 = nmad4(nx0,s0,h0); nx1 = nmad4(nx1,s1,h1);
                nx2 = nmad4(nx2,s0,h0); nx3 = nmad4(nx3,s1,h1);
            }
            nw0 = *(const float4*)(wp + kk);  nw1 = *(const float4*)(wp + kk + 4);
        }
        __builtin_amdgcn_s_setprio(1);
        #pragma unroll
        for (int ks = 0; ks < 2; ++ks) {
            bf16x8 af = __builtin_bit_cast(bf16x8, xl[cur][(ks*4 + g)*64 + ((w*16 + nl) ^ (g << 1))]);
            #pragma unroll
            for (int nf = 0; nf < 2; ++nf) {
                bf16x8 bfr = __builtin_bit_cast(bf16x8, wl[cur][(ks*4 + g)*32 + ((nf*16 + nl) ^ (g << 1))]);
                acc[nf] = __builtin_amdgcn_mfma_f32_16x16x32_bf16(af, bfr, acc[nf], 0, 0, 0);
            }
        }
        __builtin_amdgcn_s_setprio(0);
        if (nxt) {
            xl[cur^1][d0] = pack8(nx0, nx1); xl[cur^1][d1] = pack8(nx2, nx3);
            wl[cur^1][dw] = pack8(nw0, nw1);
        }
        __syncthreads();
    }

    float colS[2] = {0.f,0.f}, colQ[2] = {0.f,0.f};
    #pragma unroll
    for (int nf = 0; nf < 2; ++nf) {
        const int col = bn + nf*16 + nl;
        const float bb = bias[col];
        float rs = 1.f, rh = 0.f;
        if (norm_r) { rs = nsc[col]; rh = nsh[col]; }
        #pragma unroll
        for (int r = 0; r < 4; ++r) {
            const int row = bm + w*16 + g*4 + r;
            float v = acc[nf][r] + bb;
            if (resid) {
                float rv = resid[(size_t)row*N + col];
                v += norm_r ? fmaf(rv, rs, rh) : rv;
            }
            v *= scale;
            if (do_relu) v = fmaxf(v, 0.f);
            C[(size_t)row*N + col] = v;
            colS[nf] += v;
            colQ[nf] = fmaf(v, v, colQ[nf]);
        }
    }
    if (psum) {
        float* cs = (float*)&xl[0][0];
        float* cq = cs + 512;
        #pragma unroll
        for (int nf = 0; nf < 2; ++nf) {
            const int idx = (w*4 + g)*32 + nf*16 + nl;
            cs[idx] = colS[nf];
            cq[idx] = colQ[nf];
        }
        __syncthreads();
        if (t < 32) {
            float s = 0.f, q = 0.f;
            #pragma unroll
            for (int i = 0; i < 16; ++i) { s += cs[i*32 + t]; q += cq[i*32 + t]; }
            psum[blockIdx.x*HID + bn + t] = s;
            pq[blockIdx.x*HID + bn + t]   = q;
        }
    }
}

// ---------------------------------------------------------------------------
// Wo GEMM (64x32 tiles) with fused split-m combine from bf16 Opart
// (d'-permuted layout); W staged with the matching permutation. bn1 partials.
// ---------------------------------------------------------------------------
__launch_bounds__(256)
__global__ void gemm_wo(const __bf16* __restrict__ Opart, const float* __restrict__ Lpart,
                        int nsplit, const float* __restrict__ W,
                        const float* __restrict__ bias, const float* __restrict__ resid,
                        float* __restrict__ C, float* __restrict__ psum, float* __restrict__ pq) {
    const int N = 256, K = 256;
    __shared__ uint4 xl[2][512];
    __shared__ uint4 wl[2][256];
    const int bm = blockIdx.x * 64, bn = blockIdx.y * 32;
    const int t = threadIdx.x;
    const int w = t >> 6, l = t & 63, g = l >> 4, nl = l & 15;
    const int srow = t >> 3, seg = t & 7;
    const int sx = (seg & 3) << 1;
    const int d0 = seg*64 + (srow ^ sx);
    const int d1 = seg*64 + ((srow + 32) ^ sx);
    const int dw = seg*32 + (srow ^ sx);
    const float* wrow = W + (size_t)(bn + srow)*K;

    auto cl = [&](int row, int kp, float4& a, float4& b) {
        const size_t flat = (size_t)row*256 + kp;
        const int hn = (int)(flat >> 5);
        float L = 0.f;
        float s0=0,s1=0,s2=0,s3=0,s4=0,s5=0,s6=0,s7=0;
        for (int z = 0; z < nsplit; ++z) {
            L += Lpart[z*32768 + hn];
            uint4 u = *(const uint4*)(Opart + (size_t)z*1048576 + flat);
            s0 += bflo(u.x); s1 += bfhi(u.x);
            s2 += bflo(u.y); s3 += bfhi(u.y);
            s4 += bflo(u.z); s5 += bfhi(u.z);
            s6 += bflo(u.w); s7 += bfhi(u.w);
        }
        const float inv = 1.f / L;
        a = make_float4(s0*inv, s1*inv, s2*inv, s3*inv);
        b = make_float4(s4*inv, s5*inv, s6*inv, s7*inv);
    };
    auto wld = [&](int kp, float4& a, float4& b) {
        const int kb = (kp & ~31) + ((kp >> 3) & 3)*4;
        a = *(const float4*)(wrow + kb);
        b = *(const float4*)(wrow + kb + 16);
    };

    f32x4 acc[2];
    acc[0] = (f32x4){0.f,0.f,0.f,0.f};
    acc[1] = (f32x4){0.f,0.f,0.f,0.f};

    {
        float4 x0, x1, x2, x3, w0, w1;
        cl(bm + srow,      seg*8, x0, x1);
        cl(bm + srow + 32, seg*8, x2, x3);
        wld(seg*8, w0, w1);
        xl[0][d0] = pack8(x0, x1); xl[0][d1] = pack8(x2, x3);
        wl[0][dw] = pack8(w0, w1);
    }
    __syncthreads();

    for (int k0 = 0; k0 < K; k0 += 64) {
        const int cur = (k0 >> 6) & 1;
        const bool nxt = (k0 + 64) < K;
        float4 nx0, nx1, nx2, nx3, nw0, nw1;
        if (nxt) {
            const int kp = k0 + 64 + seg*8;
            cl(bm + srow,      kp, nx0, nx1);
            cl(bm + srow + 32, kp, nx2, nx3);
            wld(kp, nw0, nw1);
        }
        __builtin_amdgcn_s_setprio(1);
        #pragma unroll
        for (int ks = 0; ks < 2; ++ks) {
            bf16x8 af = __builtin_bit_cast(bf16x8, xl[cur][(ks*4 + g)*64 + ((w*16 + nl) ^ (g << 1))]);
            #pragma unroll
            for (int nf = 0; nf < 2; ++nf) {
                bf16x8 bfr = __builtin_bit_cast(bf16x8, wl[cur][(ks*4 + g)*32 + ((nf*16 + nl) ^ (g << 1))]);
                acc[nf] = __builtin_amdgcn_mfma_f32_16x16x32_bf16(af, bfr, acc[nf], 0, 0, 0);
            }
        }
        __builtin_amdgcn_s_setprio(0);
        if (nxt) {
            xl[cur^1][d0] = pack8(nx0, nx1); xl[cur^1][d1] = pack8(nx2, nx3);
            wl[cur^1][dw] = pack8(nw0, nw1);
        }
        __syncthreads();
    }

    float colS[2] = {0.f,0.f}, colQ[2] = {0.f,0.f};
    #pragma unroll
    for (int nf = 0; nf < 2; ++nf) {
        const int col = bn + nf*16 + nl;
        const float bb = bias[col];
        #pragma unroll
        for (int r = 0; r < 4; ++r) {
            const int row = bm + w*16 + g*4 + r;
            float v = acc[nf][r] + bb + resid[(size_t)row*N + col];
            C[(size_t)row*N + col] = v;
            colS[nf] += v;
            colQ[nf] = fmaf(v, v, colQ[nf]);
        }
    }
    {
        float* cs = (float*)&xl[0][0];
        float* cq = cs + 512;
        #pragma unroll
        for (int nf = 0; nf < 2; ++nf) {
            const int idx = (w*4 + g)*32 + nf*16 + nl;
            cs[idx] = colS[nf];
            cq[idx] = colQ[nf];
        }
        __syncthreads();
        if (t < 32) {
            float s = 0.f, q = 0.f;
            #pragma unroll
            for (int i = 0; i < 16; ++i) { s += cs[i*32 + t]; q += cq[i*32 + t]; }
            psum[blockIdx.x*HID + bn + t] = s;
            pq[blockIdx.x*HID + bn + t]   = q;
        }
    }
}

// ---------------------------------------------------------------------------
// Fused QKV3 (64x32 tiles, ONE kernel): X tile staged once per k-step for all
// three projections. q/k write bf16 hat [h][n][32]; v writes vT directly.
// ---------------------------------------------------------------------------
__launch_bounds__(256)
__global__ void gemm_qkv3(const float* __restrict__ X,
                          const float* __restrict__ Wq, const float* __restrict__ Wk,
                          const float* __restrict__ Wv, const float* __restrict__ bq,
                          const float* __restrict__ bk, const float* __restrict__ bv,
                          __bf16* __restrict__ qhat, __bf16* __restrict__ khat,
                          __bf16* __restrict__ vT) {
    const int K = 256;
    __shared__ uint4 xl[2][512];
    __shared__ uint4 wql[2][256];
    __shared__ uint4 wkl[2][256];
    __shared__ uint4 wvl[2][256];
    const int bm = blockIdx.x * 64, bn = blockIdx.y * 32;
    const int t = threadIdx.x;
    const int w = t >> 6, l = t & 63, g = l >> 4, nl = l & 15;
    const int srow = t >> 3, seg = t & 7;
    const int sx = (seg & 3) << 1;
    const int d0 = seg*64 + (srow ^ sx);
    const int d1 = seg*64 + ((srow + 32) ^ sx);
    const int dw = seg*32 + (srow ^ sx);
    const float* xp  = X  + (size_t)(bm + srow)*K + seg*8;
    const float* wqp = Wq + (size_t)(bn + srow)*K + seg*8;
    const float* wkp = Wk + (size_t)(bn + srow)*K + seg*8;
    const float* wvp = Wv + (size_t)(bn + srow)*K + seg*8;
    const size_t rstep = (size_t)32*K;

    f32x4 aq[2], ak[2], av[2];
    #pragma unroll
    for (int nf = 0; nf < 2; ++nf) {
        aq[nf] = (f32x4){0.f,0.f,0.f,0.f};
        ak[nf] = (f32x4){0.f,0.f,0.f,0.f};
        av[nf] = (f32x4){0.f,0.f,0.f,0.f};
    }

    {
        float4 x0 = *(const float4*)(xp),          x1 = *(const float4*)(xp + 4);
        float4 x2 = *(const float4*)(xp + rstep),  x3 = *(const float4*)(xp + rstep + 4);
        float4 q0 = *(const float4*)(wqp), q1 = *(const float4*)(wqp + 4);
        float4 k0 = *(const float4*)(wkp), k1 = *(const float4*)(wkp + 4);
        float4 v0 = *(const float4*)(wvp), v1 = *(const float4*)(wvp + 4);
        xl[0][d0] = pack8(x0, x1); xl[0][d1] = pack8(x2, x3);
        wql[0][dw] = pack8(q0, q1);
        wkl[0][dw] = pack8(k0, k1);
        wvl[0][dw] = pack8(v0, v1);
    }
    __syncthreads();

    for (int k0 = 0; k0 < K; k0 += 64) {
        const int cur = (k0 >> 6) & 1;
        const bool nxt = (k0 + 64) < K;
        float4 nx0, nx1, nx2, nx3, nq0, nq1, nk0, nk1, nv0, nv1;
        if (nxt) {
            const int kk = k0 + 64;
            nx0 = *(const float4*)(xp + kk);          nx1 = *(const float4*)(xp + kk + 4);
            nx2 = *(const float4*)(xp + rstep + kk);  nx3 = *(const float4*)(xp + rstep + kk + 4);
            nq0 = *(const float4*)(wqp + kk);  nq1 = *(const float4*)(wqp + kk + 4);
            nk0 = *(const float4*)(wkp + kk);  nk1 = *(const float4*)(wkp + kk + 4);
            nv0 = *(const float4*)(wvp + kk);  nv1 = *(const float4*)(wvp + kk + 4);
        }
        __builtin_amdgcn_s_setprio(1);
        #pragma unroll
        for (int ks = 0; ks < 2; ++ks) {
            bf16x8 af = __builtin_bit_cast(bf16x8, xl[cur][(ks*4 + g)*64 + ((w*16 + nl) ^ (g << 1))]);
            #pragma unroll
            for (int nf = 0; nf < 2; ++nf) {
                const int wi = (ks*4 + g)*32 + ((nf*16 + nl) ^ (g << 1));
                bf16x8 bq8 = __builtin_bit_cast(bf16x8, wql[cur][wi]);
                bf16x8 bk8 = __builtin_bit_cast(bf16x8, wkl[cur][wi]);
                bf16x8 bv8 = __builtin_bit_cast(bf16x8, wvl[cur][wi]);
                aq[nf] = __builtin_amdgcn_mfma_f32_16x16x32_bf16(af, bq8, aq[nf], 0, 0, 0);
                ak[nf] = __builtin_amdgcn_mfma_f32_16x16x32_bf16(af, bk8, ak[nf], 0, 0, 0);
                av[nf] = __builtin_amdgcn_mfma_f32_16x16x32_bf16(af, bv8, av[nf], 0, 0, 0);
            }
        }
        __builtin_amdgcn_s_setprio(0);
        if (nxt) {
            xl[cur^1][d0] = pack8(nx0, nx1); xl[cur^1][d1] = pack8(nx2, nx3);
            wql[cur^1][dw] = pack8(nq0, nq1);
            wkl[cur^1][dw] = pack8(nk0, nk1);
            wvl[cur^1][dw] = pack8(nv0, nv1);
        }
        __syncthreads();
    }

    const float qscale = 0.25506595325f;   // 32^-0.5 * log2(e)
    #pragma unroll
    for (int nf = 0; nf < 2; ++nf) {
        const int col = bn + nf*16 + nl;
        const float bbq = bq[col], bbk = bk[col], bbv = bv[col];
        const int dd = col & 31;
        #pragma unroll
        for (int r = 0; r < 4; ++r) {
            const int row = bm + w*16 + g*4 + r;
            const int hh = row >> 9;
            const int nn = ((row & 511) << 3) | (col >> 5);
            qhat[((size_t)(hh*4096 + nn))*32 + dd] = (__bf16)((aq[nf][r] + bbq) * qscale);
            khat[((size_t)(hh*4096 + nn))*32 + dd] = (__bf16)(ak[nf][r] + bbk);
            vT[((size_t)(hh*32 + dd))*4096 + nn]   = (__bf16)(av[nf][r] + bbv);
        }
    }
}

// ---------------------------------------------------------------------------
// All-heads flash attention (best-measured R17/R18/R22 structure): block =
// (64-query tile, z-split), 512 threads, 8 waves = 8 heads. A tile staged once
// in LDS for all heads; batched step loads + sched_barrier pin; bf16 d'-packed
// Opart with coalesced 16B stores.
// ---------------------------------------------------------------------------
__launch_bounds__(512, 2)
__global__ void attn_mfma(const __bf16* __restrict__ qh_, const __bf16* __restrict__ kh,
                          const __bf16* __restrict__ vT, const float* __restrict__ A,
                          __bf16* __restrict__ Opart, float* __restrict__ Lpart, int mlen) {
    __shared__ float A_lds[2][64][68];       // 34.8 KB, shared by all 8 heads
    __shared__ uint4 p_lds[8][4][64];        // 32 KB, per-wave P exchange

    const int t = threadIdx.x;
    const int w = t >> 6, l = t & 63;        // wave = head
    const int g = l >> 4, nl = l & 15;
    const int n0 = blockIdx.x * 64;
    const int z = blockIdx.y;
    const int m_begin = z * mlen;
    const int nsteps = mlen >> 6;

    bf16x8 qf[4];
    #pragma unroll
    for (int nf = 0; nf < 4; ++nf)
        qf[nf] = *(const bf16x8*)(qh_ + ((size_t)(w*4096 + n0 + nf*16 + nl))*32 + g*8);

    f32x4 oacc[4][2];
    #pragma unroll
    for (int nf = 0; nf < 4; ++nf) {
        oacc[nf][0] = (f32x4){0.f,0.f,0.f,0.f};
        oacc[nf][1] = (f32x4){0.f,0.f,0.f,0.f};
    }
    float Li[4] = {0.f, 0.f, 0.f, 0.f};

    const int aq = t >> 3, am = (t & 7) * 8;
    const float* Abase = A + (size_t)(n0 + aq)*N_NODES + m_begin + am;
    const __bf16* kbase = kh + ((size_t)w*4096 + nl)*32 + g*8;
    const __bf16* vbase = vT + ((size_t)w*32 + nl)*4096 + g*8;

    *(float4*)&A_lds[0][aq][am]   = *(const float4*)(Abase);
    *(float4*)&A_lds[0][aq][am+4] = *(const float4*)(Abase + 4);
    __syncthreads();

    for (int s = 0; s < nsteps; ++s) {
        const int cur = s & 1;
        const int m0 = m_begin + s*64;
        const bool nxt = (s + 1) < nsteps;
        float4 a0n, a1n;
        if (nxt) {
            a0n = *(const float4*)(Abase + (s+1)*64);
            a1n = *(const float4*)(Abase + (s+1)*64 + 4);
        }
        // batch-issue ALL current-step K/V fragments, pin the issue point
        bf16x8 kf[4], vf[4];
        #pragma unroll
        for (int tt = 0; tt < 4; ++tt)
            kf[tt] = *(const bf16x8*)(kbase + (size_t)(m0 + tt*16)*32);
        #pragma unroll
        for (int half = 0; half < 2; ++half)
            #pragma unroll
            for (int dt = 0; dt < 2; ++dt)
                vf[half*2+dt] = *(const bf16x8*)(vbase + (size_t)dt*16*4096 + m0 + half*32);
        __builtin_amdgcn_sched_barrier(0);

        #pragma unroll
        for (int half = 0; half < 2; ++half) {
            #pragma unroll
            for (int tt2 = 0; tt2 < 2; ++tt2) {
                const int tt = half*2 + tt2;
                f32x4 st[4];
                __builtin_amdgcn_s_setprio(1);
                #pragma unroll
                for (int nf = 0; nf < 4; ++nf) {
                    f32x4 zz = (f32x4){0.f,0.f,0.f,0.f};
                    st[nf] = __builtin_amdgcn_mfma_f32_16x16x32_bf16(kf[tt], qf[nf], zz, 0, 0, 0);
                }
                __builtin_amdgcn_s_setprio(0);
                #pragma unroll
                for (int nf = 0; nf < 4; ++nf) {
                    const f32x4 a4 = *(const f32x4*)&A_lds[cur][nf*16 + nl][tt*16 + g*4];
                    float p0 = fexp2(fmaf(st[nf][0], a4[0], -M2LOG));
                    float p1 = fexp2(fmaf(st[nf][1], a4[1], -M2LOG));
                    float p2 = fexp2(fmaf(st[nf][2], a4[2], -M2LOG));
                    float p3 = fexp2(fmaf(st[nf][3], a4[3], -M2LOG));
                    Li[nf] += (p0 + p1) + (p2 + p3);
                    bf16x4 pk;
                    pk[0] = (__bf16)p0; pk[1] = (__bf16)p1;
                    pk[2] = (__bf16)p2; pk[3] = (__bf16)p3;
                    const int gm = tt2*2 + (g >> 1);
                    *(bf16x4*)((char*)&p_lds[w][nf][0] + (gm*16 + (nl ^ (gm << 1)))*16 + (g & 1)*8) = pk;
                }
            }
            __builtin_amdgcn_s_setprio(1);
            #pragma unroll
            for (int nf = 0; nf < 4; ++nf) {
                bf16x8 pf = __builtin_bit_cast(bf16x8, p_lds[w][nf][g*16 + (nl ^ (g << 1))]);
                oacc[nf][0] = __builtin_amdgcn_mfma_f32_16x16x32_bf16(vf[half*2+0], pf, oacc[nf][0], 0, 0, 0);
                oacc[nf][1] = __builtin_amdgcn_mfma_f32_16x16x32_bf16(vf[half*2+1], pf, oacc[nf][1], 0, 0, 0);
            }
            __builtin_amdgcn_s_setprio(0);
        }

        if (nxt) {
            *(float4*)&A_lds[cur^1][aq][am]   = a0n;
            *(float4*)&A_lds[cur^1][aq][am+4] = a1n;
        }
        __syncthreads();
    }

    // epilogue: bf16 d'-packed partials (coalesced 16B stores) + L
    #pragma unroll
    for (int nf = 0; nf < 4; ++nf) {
        Li[nf] += __shfl_xor(Li[nf], 16);
        Li[nf] += __shfl_xor(Li[nf], 32);
        const int nq = n0 + nf*16 + nl;
        __bf16* ob = Opart + ((size_t)(z*NHEADS + w)*4096 + nq)*32;
        bf16x8 pk8;
        #pragma unroll
        for (int j = 0; j < 4; ++j) {
            pk8[j]     = (__bf16)oacc[nf][0][j];
            pk8[4 + j] = (__bf16)oacc[nf][1][j];
        }
        *(bf16x8*)(ob + g*8) = pk8;
        if (g == 0)
            Lpart[(z*NHEADS + w)*4096 + nq] = Li[nf];
    }
}

// ---------------------------------------------------------------------------
// Fused BatchNorm finalize + apply: per-block stats reduce, then apply.
// ---------------------------------------------------------------------------
__launch_bounds__(256)
__global__ void bnorm_fin_apply(const float* __restrict__ X,
                                const float* __restrict__ pS, const float* __restrict__ pQ,
                                const float* __restrict__ gam, const float* __restrict__ bet,
                                float* __restrict__ Y) {
    __shared__ __align__(16) float sc[256];
    __shared__ __align__(16) float sh[256];
    const int t = threadIdx.x;
    {
        float s = 0.f, q = 0.f;
        #pragma unroll 8
        for (int b = 0; b < 64; ++b) { s += pS[b*HID + t]; q += pQ[b*HID + t]; }
        const float m = s * (1.f/4096.f);
        const float rstd = rsqrtf(q*(1.f/4096.f) - m*m + EPSV);
        const float scv = rstd * gam[t];
        sc[t] = scv;
        sh[t] = fmaf(-m, scv, bet[t]);
    }
    __syncthreads();
    const int base0 = (blockIdx.x * 256 + t) * 16;
    #pragma unroll
    for (int j = 0; j < 4; ++j) {
        const int base = base0 + j*4;
        const int c = base & (HID - 1);
        float4 x = *(const float4*)(X + base);
        float4 o;
        o.x = fmaf(x.x, sc[c+0], sh[c+0]);
        o.y = fmaf(x.y, sc[c+1], sh[c+1]);
        o.z = fmaf(x.z, sc[c+2], sh[c+2]);
        o.w = fmaf(x.w, sc[c+3], sh[c+3]);
        *(float4*)(Y + base) = o;
    }
}

// ---------------------------------------------------------------------------
extern "C" void kernel_launch(void* const* d_in, const int* in_sizes, int n_in,
                              void* d_out, int out_size, void* d_ws, size_t ws_size,
                              hipStream_t stream) {
    const float* A  = (const float*)d_in[0];
    const float* h  = (const float*)d_in[1];
    const float* Wq = (const float*)d_in[2];
    const float* bq = (const float*)d_in[3];
    const float* Wk = (const float*)d_in[4];
    const float* bk = (const float*)d_in[5];
    const float* Wv = (const float*)d_in[6];
    const float* bv = (const float*)d_in[7];
    const float* Wo = (const float*)d_in[8];
    const float* bo = (const float*)d_in[9];
    const float* W1 = (const float*)d_in[10];
    const float* c1 = (const float*)d_in[11];
    const float* W2 = (const float*)d_in[12];
    const float* c2 = (const float*)d_in[13];
    const float* g1 = (const float*)d_in[14];
    const float* be1= (const float*)d_in[15];
    const float* g2 = (const float*)d_in[16];
    const float* be2= (const float*)d_in[17];

    char* wsb = (char*)d_ws;
    const size_t MiB = (size_t)1 << 20;
    // Opart bf16: nsplit*2 MiB at offset 8 MiB.
    const int nsplit = (ws_size >= 26*MiB) ? 8 : (ws_size >= 18*MiB) ? 4 : 2;
    const int mlen = N_NODES / nsplit;

    __bf16* qhat = (__bf16*)(wsb + 0*MiB);
    __bf16* khat = (__bf16*)(wsb + 2*MiB);
    __bf16* vT   = (__bf16*)(wsb + 4*MiB);          // 2 MiB
    __bf16* Opart = (__bf16*)(wsb + 8*MiB);         // nsplit*2 MiB
    float* Lpart = (float*)(wsb + 8*MiB + (size_t)nsplit*2*MiB);
    char* statb  = wsb + 8*MiB + (size_t)nsplit*2*MiB + 1*MiB;
    float* partS1 = (float*)statb;
    float* partQ1 = partS1 + 64*HID;
    float* partS2 = partQ1 + 64*HID;
    float* partQ2 = partS2 + 64*HID;
    float* Y1 = (float*)(wsb + 4*MiB);   // over dead vT (4..8 MiB)
    float* F1 = (float*)(wsb + 8*MiB);   // over dead Opart (8..16 MiB)
    float* Y2 = (float*)(wsb + 0*MiB);   // over dead q/k hats (0..4 MiB)

    // QKV fused: X staged once for q/k/v; V transposed in epilogue
    gemm_qkv3<<<dim3(64, 8), 256, 0, stream>>>(h, Wq, Wk, Wv, bq, bk, bv, qhat, khat, vT);

    // all-heads split-m attention (A read-once, batched loads, bf16 Opart)
    attn_mfma<<<dim3(64, nsplit), 512, 0, stream>>>(qhat, khat, vT, A, Opart, Lpart, mlen);

    // Wo projection with fused combine (permuted W staging) + residual(h) + bn1 partials
    gemm_wo<<<dim3(64, 8), 256, 0, stream>>>(Opart, Lpart, nsplit, Wo, bo, h, Y1, partS1, partQ1);

    // FFN1: X = bnorm1(Y1) computed per-block from partials, staged on the fly
    gemm_mfma<<<dim3(64, 16), 256, 0, stream>>>(Y1, W1, c1, nullptr, F1,
                                                partS1, partQ1, g1, be1, 1, 0,
                                                nullptr, nullptr, 4096, 512, 256, 1.f, 1);
    // FFN2: + bnorm1(Y1) residual, bnorm2 partials in epilogue
    gemm_mfma<<<dim3(64, 8), 256, 0, stream>>>(F1, W2, c2, Y1, Y2,
                                               partS1, partQ1, g1, be1, 0, 1,
                                               partS2, partQ2, 4096, 256, 512, 1.f, 0);

    // fused bnorm2 finalize + apply -> output
    bnorm_fin_apply<<<256, 256, 0, stream>>>(Y2, partS2, partQ2, g2, be2, (float*)d_out);
}